// Round 16
// baseline (89.808 us; speedup 1.0000x reference)
//
#include <hip/hip_runtime.h>
#include <hip/hip_bf16.h>

#define NB 8
#define NN 256
#define DIMV 256
#define DI 64
#define NEGMAX 3.402823466e+38f
#define LOG2E 1.44269504088896f

typedef unsigned short u16;
typedef unsigned int u32;
typedef __attribute__((ext_vector_type(8))) short bf16x8;
typedef __attribute__((ext_vector_type(4))) float f32x4;
typedef __attribute__((ext_vector_type(2))) float f32x2;
typedef __attribute__((ext_vector_type(2))) unsigned int u32x2;

__device__ __forceinline__ u16 f2bf(float f) {
    __hip_bfloat16 h = __float2bfloat16(f);
    u16 u; __builtin_memcpy(&u, &h, 2); return u;
}
__device__ __forceinline__ u32 pack2(float a, float b) {
    return (u32)f2bf(a) | ((u32)f2bf(b) << 16);
}
__device__ __forceinline__ float ubf_lo(u32 u) {
    union { u32 u; float f; } x; x.u = u << 16; return x.f;
}
__device__ __forceinline__ float ubf_hi(u32 u) {
    union { u32 u; float f; } x; x.u = u & 0xffff0000u; return x.f;
}
// swizzles: fA for 128B-stride rows, fB for 64B-stride rows (bits 4-6 only)
__device__ __forceinline__ int fA(int row) { return ((row & 7) << 4) ^ ((row & 8) << 2); }
__device__ __forceinline__ int fB(int row) { return ((row >> 1) & 7) << 4; }

// ---------------------------------------------------------------------------
// merged prep, 576 blocks: [0,512) = qkv; [512,576) = fragment-major weights
// (w2s pre-scaled by log2(e): sim's only consumer is exp -> exp2 in kernel)
// + out_wT transpose for vectorized output loads.
// ---------------------------------------------------------------------------
__global__ void prep_all(const float* __restrict__ x, const float* __restrict__ y,
                         const float* __restrict__ tw, const float* __restrict__ pw,
                         const float* __restrict__ gw,
                         const float* __restrict__ w1, const float* __restrict__ w2,
                         const float* __restrict__ pw2,
                         const float* __restrict__ pw1, const float* __restrict__ pb1,
                         const float* __restrict__ ow,
                         float* __restrict__ q, float* __restrict__ k, float* __restrict__ v,
                         u16* __restrict__ w1s, u16* __restrict__ w2s,
                         u16* __restrict__ pw2s, u16* __restrict__ pw1f,
                         float* __restrict__ out_wT)
{
    __shared__ float xs[4][256];
    __shared__ float ys[4][256];
    const int blk = blockIdx.x;
    const int tid = threadIdx.x;

    if (blk >= 512) {                       // ---- weight fragments ----
        const int idx = (blk - 512) * 256 + tid;   // [0,16384)
        const int e   = idx & 7;
        const int l   = (idx >> 3) & 63;
        const int l15 = l & 15, lh = l >> 4;
        {   // w1s
            const int frag = idx >> 9;      // 0..31
            const int ks = frag & 1, c2 = (frag >> 1) & 1, hc = frag >> 2;
            w1s[idx] = f2bf(w1[(ks * 32 + lh * 8 + e) * 256 + hc * 32 + 2 * l15 + c2]);
        }
        {   // w2s (scaled by log2e for exp2 softmax)
            const int frag = idx >> 9;      // 0..31
            const int ct = frag & 3, hc = frag >> 2;
            w2s[idx] = f2bf(w2[(hc * 32 + lh * 8 + e) * 64 + 4 * l15 + ct] * LOG2E);
        }
        {   // out_wT[c][d] = out_w[d][c]
            const int c = idx >> 6, d = idx & 63;
            out_wT[idx] = ow[d * 256 + c];
        }
        if (idx < 4096) {                   // pw2s
            const int frag = idx >> 9;      // 0..7
            const int ks = frag & 1, ct = frag >> 1;
            pw2s[idx] = f2bf(pw2[(ks * 32 + lh * 8 + e) * 64 + 4 * l15 + ct]);
        }
        if (idx < 2048) {                   // pw1f (augmented, K=32 padded)
            const int ct = idx >> 9;        // 0..3
            const int kk = lh * 8 + e;
            const int col = 4 * l15 + ct;
            float val = (kk < 3) ? pw1[kk * 64 + col] : ((kk == 3) ? pb1[col] : 0.f);
            pw1f[idx] = f2bf(val);
        }
        return;
    }

    // ---- qkv: b = blk>>6, 4 rows, thread = (nl, d) ----
    const int b = blk >> 6;
    const int n0 = (blk & 63) * 4;
    {
        int r = tid >> 6, e = tid & 63;
        ((float4*)xs[r])[e] = ((const float4*)(x + (size_t)(b * NN + n0 + r) * DIMV))[e];
        ((float4*)ys[r])[e] = ((const float4*)(y + (size_t)(b * NN + n0 + r) * DIMV))[e];
    }
    __syncthreads();
    const int nl = tid >> 6, d = tid & 63;
    float aq = 0.f, ak = 0.f, av = 0.f;
    #pragma unroll 4
    for (int c = 0; c < 256; ++c) {
        float wq = tw[c * 64 + d], wk = pw[c * 64 + d], wv = gw[c * 64 + d];
        float xv = xs[nl][c], yv = ys[nl][c];
        aq += xv * wq; ak += yv * wk; av += yv * wv;
    }
    const int n = n0 + nl;
    q[(b * NN + n) * DI + d] = aq;
    k[(b * NN + n) * DI + d] = ak;
    v[(b * NN + n) * DI + d] = av;
}

// ---------------------------------------------------------------------------
// main fused kernel: one block per (b, i); 4 waves; wave owns rows j0..j0+63.
// r13 structure (best: 76.5us) + select-on-read mask (r14's good half) +
// exp2 softmax (w2/ab2 pre-scaled by log2e) + vectorized out_wT tail.
// ---------------------------------------------------------------------------
__global__ __launch_bounds__(256, 2)
void fused_attn(const float* __restrict__ x, const float* __restrict__ x_pos,
                const float* __restrict__ y_pos, const int* __restrict__ mask,
                const float* __restrict__ pb2,
                const float* __restrict__ ab1, const float* __restrict__ ab2,
                const float* __restrict__ out_wT,
                const float* __restrict__ qg, const float* __restrict__ kg,
                const float* __restrict__ vg,
                const u16* __restrict__ w1s, const u16* __restrict__ w2s,
                const u16* __restrict__ pw2s, const u16* __restrict__ pw1f,
                float* __restrict__ out)
{
    __shared__ __align__(16) char sT[4][8192];     // 32 KB
    __shared__ __align__(16) char sHid[4][4096];   // 16 KB (hid dbuf -> Hc -> red)
    __shared__ __align__(16) char sV2[4][4096];    // 16 KB

    const int blk = blockIdx.x;
    const int b = blk >> 8;
    const int i = blk & 255;
    const int tid = threadIdx.x;
    const int l   = tid & 63;
    const int w   = tid >> 6;
    const int j0  = w * 64;
    const int l15 = l & 15;
    const int lh  = l >> 4;

    char* const sTw   = sT[w];
    char* const sHidw = sHid[w];
    char* const sV2w  = sV2[w];

    // hoisted LDS addresses
    int stW[4], hcW[4];
    #pragma unroll
    for (int r = 0; r < 4; ++r) {
        const int lr = lh * 4 + r;
        stW[r] = (lr * 128 + l15 * 8) ^ fA(lr);
        hcW[r] = (lr * 64 + l15 * 4) ^ fB(lr);
    }
    const int stR0 = (l15 * 128 + lh * 16) ^ fA(l15);
    const int stR1 = stR0 ^ 64;
    const int hcR  = (l15 * 64 + lh * 16) ^ fB(l15);

    // ---- mask ----
    const int mjl = mask[b * NN + j0 + l];
    const unsigned long long mb = __ballot(mjl != 0);
    const bool mi_b = mask[b * NN + i] != 0;

    // ---- phase 0: rel-pos A-fragments (bias-in-K: [r0,r1,r2,1,0..0]) ----
    const float xp0 = x_pos[(b * NN + i) * 3 + 0];
    const float xp1 = x_pos[(b * NN + i) * 3 + 1];
    const float xp2 = x_pos[(b * NN + i) * 3 + 2];

    bf16x8 afr[4];
    #pragma unroll
    for (int rt = 0; rt < 4; ++rt) {
        const float* yp = y_pos + (size_t)(b * NN + j0 + rt * 16 + l15) * 3;
        const float r0 = xp0 - yp[0], r1 = xp1 - yp[1], r2 = xp2 - yp[2];
        union { u32 u[4]; bf16x8 v; } c;
        c.u[0] = (lh == 0) ? pack2(r0, r1) : 0u;
        c.u[1] = (lh == 0) ? pack2(r2, 1.0f) : 0u;
        c.u[2] = 0u; c.u[3] = 0u;
        afr[rt] = c.v;
    }
    bf16x8 pw1b[4];
    #pragma unroll
    for (int ct = 0; ct < 4; ++ct)
        pw1b[ct] = *(const bf16x8*)(pw1f + (ct * 64 + l) * 8);

    const f32x4 qv   = *(const f32x4*)&qg[((size_t)b * NN + i) * DI + 4 * l15];
    const f32x4 pb2v = *(const f32x4*)&pb2[4 * l15];
    bf16x8 bfr[4][2];
    #pragma unroll
    for (int ct = 0; ct < 4; ++ct)
        #pragma unroll
        for (int ks = 0; ks < 2; ++ks)
            bfr[ct][ks] = *(const bf16x8*)(pw2s + ((ct * 2 + ks) * 64 + l) * 8);

    // hidden pipeline helpers (hA transient; dbuf in sHidw)
    f32x4 hA[4];
    #define HID_MFMA(RT)                                                        \
        { _Pragma("unroll") for (int ct = 0; ct < 4; ++ct) {                    \
            f32x4 z = {0.f, 0.f, 0.f, 0.f};                                     \
            hA[ct] = __builtin_amdgcn_mfma_f32_16x16x32_bf16(afr[RT], pw1b[ct], z, 0, 0, 0); } }
    #define HID_STORE(RT)                                                       \
        { char* hb = sHidw + (((RT) & 1) ? 2048 : 0);                           \
          _Pragma("unroll") for (int r = 0; r < 4; ++r) {                       \
            u32x2 hpk;                                                          \
            hpk[0] = pack2(fmaxf(hA[0][r], 0.f), fmaxf(hA[1][r], 0.f));         \
            hpk[1] = pack2(fmaxf(hA[2][r], 0.f), fmaxf(hA[3][r], 0.f));         \
            *(u32x2*)(hb + stW[r]) = hpk; } }

    // ---- rt loop: hid(rt+1) pipelined against GEMM0(rt)+epilogue(rt) ----
    u32x2 accVp[2][4];
    HID_MFMA(0);
    HID_STORE(0);
    #pragma unroll
    for (int rt = 0; rt < 4; ++rt) {
        if (rt < 3) { HID_MFMA(rt + 1); HID_STORE(rt + 1); }
        char* const hb = sHidw + ((rt & 1) ? 2048 : 0);
        const bf16x8 afc0 = *(const bf16x8*)(hb + stR0);
        const bf16x8 afc1 = *(const bf16x8*)(hb + stR1);

        // GEMM0: RPE = hidden @ pos_w2 (pb2 folded into acc init)
        f32x4 accR[4];
        #pragma unroll
        for (int ct = 0; ct < 4; ++ct) {
            f32x4 a = {pb2v[ct], pb2v[ct], pb2v[ct], pb2v[ct]};
            a = __builtin_amdgcn_mfma_f32_16x16x32_bf16(afc0, bfr[ct][0], a, 0, 0, 0);
            a = __builtin_amdgcn_mfma_f32_16x16x32_bf16(afc1, bfr[ct][1], a, 0, 0, 0);
            accR[ct] = a;
        }
        #pragma unroll
        for (int r = 0; r < 4; ++r) {
            const int row = j0 + rt * 16 + lh * 4 + r;
            const f32x4 kv = *(const f32x4*)&kg[((size_t)b * NN + row) * DI + 4 * l15];
            const f32x4 vv = *(const f32x4*)&vg[((size_t)b * NN + row) * DI + 4 * l15];
            float tv[4], vf[4];
            #pragma unroll
            for (int ct = 0; ct < 4; ++ct) {
                const float rpe = accR[ct][r];
                tv[ct] = qv[ct] - kv[ct] + rpe;
                vf[ct] = vv[ct] + rpe;
            }
            u32x2 tpk; tpk[0] = pack2(tv[0], tv[1]); tpk[1] = pack2(tv[2], tv[3]);
            u32x2 vpk; vpk[0] = pack2(vf[0], vf[1]); vpk[1] = pack2(vf[2], vf[3]);
            *(u32x2*)(sTw + stW[r] + rt * 2048) = tpk;      // deferred-read slice
            if (rt < 2) accVp[rt][r] = vpk;
            else        *(u32x2*)(sV2w + stW[r] + (rt - 2) * 2048) = vpk;
        }
    }

    // ---- deferred aT hoist (writes long completed -> no exposed RTT) ----
    bf16x8 aT[4][2];
    #pragma unroll
    for (int rt = 0; rt < 4; ++rt) {
        aT[rt][0] = *(const bf16x8*)(sTw + stR0 + rt * 2048);
        aT[rt][1] = *(const bf16x8*)(sTw + stR1 + rt * 2048);
    }

    // ---- chunk loop (r13 version): 8 chunks; Hc in sHidw; a2 reads hoisted ----
    const f32x4 ab2v = (*(const f32x4*)&ab2[4 * l15]) * LOG2E;   // scaled domain
    f32x4 accS[4][4];
    #pragma unroll
    for (int rt = 0; rt < 4; ++rt)
        #pragma unroll
        for (int ct = 0; ct < 4; ++ct)
            accS[rt][ct] = (f32x4){ab2v[ct], ab2v[ct], ab2v[ct], ab2v[ct]};  // ab2 folded

    #pragma unroll
    for (int hc = 0; hc < 8; ++hc) {
        bf16x8 b1f[2][2];
        #pragma unroll
        for (int c2 = 0; c2 < 2; ++c2)
            #pragma unroll
            for (int ks = 0; ks < 2; ++ks)
                b1f[c2][ks] = *(const bf16x8*)(w1s + ((hc * 4 + c2 * 2 + ks) * 64 + l) * 8);
        bf16x8 b2f[4];
        #pragma unroll
        for (int ct = 0; ct < 4; ++ct)
            b2f[ct] = *(const bf16x8*)(w2s + ((hc * 4 + ct) * 64 + l) * 8);
        const f32x2 ab1v = *(const f32x2*)&ab1[hc * 32 + 2 * l15];
        const f32x4 ib0 = {ab1v[0], ab1v[0], ab1v[0], ab1v[0]};
        const f32x4 ib1 = {ab1v[1], ab1v[1], ab1v[1], ab1v[1]};
        __builtin_amdgcn_s_setprio(1);
        #pragma unroll
        for (int rt = 0; rt < 4; ++rt) {
            f32x4 h0 = ib0, h1 = ib1;                  // ab1 folded
            h0 = __builtin_amdgcn_mfma_f32_16x16x32_bf16(aT[rt][0], b1f[0][0], h0, 0, 0, 0);
            h0 = __builtin_amdgcn_mfma_f32_16x16x32_bf16(aT[rt][1], b1f[0][1], h0, 0, 0, 0);
            h1 = __builtin_amdgcn_mfma_f32_16x16x32_bf16(aT[rt][0], b1f[1][0], h1, 0, 0, 0);
            h1 = __builtin_amdgcn_mfma_f32_16x16x32_bf16(aT[rt][1], b1f[1][1], h1, 0, 0, 0);
            #pragma unroll
            for (int r = 0; r < 4; ++r)
                *(u32*)(sHidw + hcW[r] + rt * 1024) =
                    pack2(fmaxf(h0[r], 0.f), fmaxf(h1[r], 0.f));
        }
        // hoist all 4 a2 reads ahead of the MFMA chain (batch ds latency)
        bf16x8 a2[4];
        #pragma unroll
        for (int rt = 0; rt < 4; ++rt)
            a2[rt] = *(const bf16x8*)(sHidw + hcR + rt * 1024);
        #pragma unroll
        for (int rt = 0; rt < 4; ++rt)
            #pragma unroll
            for (int ct = 0; ct < 4; ++ct)
                accS[rt][ct] = __builtin_amdgcn_mfma_f32_16x16x32_bf16(a2[rt], b2f[ct], accS[rt][ct], 0, 0, 0);
        __builtin_amdgcn_s_setprio(0);
    }

    // ---- softmax (scaled domain, exp2): select-on-read mask; wave-local max ----
    float mx[4] = {-NEGMAX, -NEGMAX, -NEGMAX, -NEGMAX};
    #pragma unroll
    for (int rt = 0; rt < 4; ++rt)
        #pragma unroll
        for (int r = 0; r < 4; ++r) {
            const int ro = rt * 16 + lh * 4 + r;
            const bool bit = mi_b && ((mb >> ro) & 1ull);
            #pragma unroll
            for (int ct = 0; ct < 4; ++ct) {
                const float s = bit ? accS[rt][ct][r] : -NEGMAX;
                mx[ct] = fmaxf(mx[ct], s);
            }
        }
    #pragma unroll
    for (int ct = 0; ct < 4; ++ct) {
        mx[ct] = fmaxf(mx[ct], __shfl_xor(mx[ct], 16));
        mx[ct] = fmaxf(mx[ct], __shfl_xor(mx[ct], 32));
    }
    float ssum[4] = {0.f, 0.f, 0.f, 0.f}, sagg[4] = {0.f, 0.f, 0.f, 0.f};
    #pragma unroll
    for (int rt = 0; rt < 4; ++rt)
        #pragma unroll
        for (int r = 0; r < 4; ++r) {
            const int ro = rt * 16 + lh * 4 + r;
            const bool bit = mi_b && ((mb >> ro) & 1ull);
            u32x2 vpk;
            if (rt < 2) vpk = accVp[rt][r];
            else        vpk = *(const u32x2*)(sV2w + stW[r] + (rt - 2) * 2048);
            const float vfs[4] = {ubf_lo(vpk[0]), ubf_hi(vpk[0]), ubf_lo(vpk[1]), ubf_hi(vpk[1])};
            #pragma unroll
            for (int ct = 0; ct < 4; ++ct) {
                const float sm = bit ? accS[rt][ct][r] : -NEGMAX;
                const float e = exp2f(sm - mx[ct]);
                ssum[ct] += e;
                sagg[ct] += e * vfs[ct];
            }
        }
    #pragma unroll
    for (int ct = 0; ct < 4; ++ct) {
        ssum[ct] += __shfl_xor(ssum[ct], 16);
        ssum[ct] += __shfl_xor(ssum[ct], 32);
        sagg[ct] += __shfl_xor(sagg[ct], 16);
        sagg[ct] += __shfl_xor(sagg[ct], 32);
    }
    // write (m, s, a) into OWN sHid slice (wave-private, dead) - pre-barrier OK
    {
        float* const redW = (float*)&sHid[w][0];
        if (lh == 0) {
            *(f32x4*)&redW[      4 * l15] = (f32x4){mx[0], mx[1], mx[2], mx[3]};
            *(f32x4*)&redW[ 64 + 4 * l15] = (f32x4){ssum[0], ssum[1], ssum[2], ssum[3]};
            *(f32x4*)&redW[128 + 4 * l15] = (f32x4){sagg[0], sagg[1], sagg[2], sagg[3]};
        }
    }
    __syncthreads();
    // flash combine (base-2): M = max m_w; den = sum s_w 2^{m_w-M}; num likewise
    float* const redAll = (float*)&sHid[0][0];     // slices at float offset w*1024
    if (tid < 64) {
        const float m0 = redAll[tid],        m1 = redAll[1024 + tid],
                    m2 = redAll[2048 + tid], m3 = redAll[3072 + tid];
        const float M = fmaxf(fmaxf(m0, m1), fmaxf(m2, m3));
        const float e0 = exp2f(m0 - M), e1 = exp2f(m1 - M),
                    e2 = exp2f(m2 - M), e3 = exp2f(m3 - M);
        const float den = redAll[64 + tid] * e0 + redAll[1024 + 64 + tid] * e1
                        + redAll[2048 + 64 + tid] * e2 + redAll[3072 + 64 + tid] * e3;
        const float num = redAll[128 + tid] * e0 + redAll[1024 + 128 + tid] * e1
                        + redAll[2048 + 128 + tid] * e2 + redAll[3072 + 128 + tid] * e3;
        redAll[192 + tid] = num / den;
    }
    __syncthreads();

    // ---- out[i,:] = x[i,:] + agg @ out_w (vectorized via out_wT) ----
    {
        float acc = 0.f;
        const f32x4* wt = (const f32x4*)(out_wT + (size_t)tid * 64);
        #pragma unroll
        for (int d4 = 0; d4 < 16; ++d4) {
            const f32x4 wv = wt[d4];
            const f32x4 ag = *(const f32x4*)&redAll[192 + d4 * 4];
            acc += ag[0] * wv[0] + ag[1] * wv[1] + ag[2] * wv[2] + ag[3] * wv[3];
        }
        const int o = (b * NN + i) * DIMV + tid;
        out[o] = x[o] + acc;
    }
}

// ---------------------------------------------------------------------------
extern "C" void kernel_launch(void* const* d_in, const int* in_sizes, int n_in,
                              void* d_out, int out_size, void* d_ws, size_t ws_size,
                              hipStream_t stream)
{
    const float* x       = (const float*)d_in[0];
    const float* y       = (const float*)d_in[1];
    const float* x_pos   = (const float*)d_in[2];
    const float* y_pos   = (const float*)d_in[3];
    const int*   mask    = (const int*)d_in[4];
    const float* g_w     = (const float*)d_in[5];
    const float* theta_w = (const float*)d_in[6];
    const float* phi_w   = (const float*)d_in[7];
    const float* pos_w1  = (const float*)d_in[8];
    const float* pos_b1  = (const float*)d_in[9];
    const float* pos_w2  = (const float*)d_in[10];
    const float* pos_b2  = (const float*)d_in[11];
    const float* attn_w1 = (const float*)d_in[12];
    const float* attn_b1 = (const float*)d_in[13];
    const float* attn_w2 = (const float*)d_in[14];
    const float* attn_b2 = (const float*)d_in[15];
    const float* out_w   = (const float*)d_in[16];

    float* q = (float*)d_ws;
    float* k = q + NB * NN * DI;
    float* v = k + NB * NN * DI;
    u16* w1s  = (u16*)(v + NB * NN * DI);   // 16384 u16 (fragment-major)
    u16* w2s  = w1s + 16384;                // 16384 u16 (scaled by log2e)
    u16* pw2s = w2s + 16384;                // 4096 u16
    u16* pw1f = pw2s + 4096;                // 2048 u16
    float* out_wT = (float*)(pw1f + 2048);  // 16384 f32 (transposed out_w)

    prep_all<<<576, 256, 0, stream>>>(x, y, theta_w, phi_w, g_w,
                                      attn_w1, attn_w2, pos_w2, pos_w1, pos_b1,
                                      out_w,
                                      q, k, v, w1s, w2s, pw2s, pw1f, out_wT);
    fused_attn<<<NB * NN, 256, 0, stream>>>(x, x_pos, y_pos, mask,
                                            pos_b2, attn_b1, attn_b2, out_wT,
                                            q, k, v, w1s, w2s, pw2s, pw1f,
                                            (float*)d_out);
}

// Round 17
// 80.653 us; speedup vs baseline: 1.1135x; 1.1135x over previous
//
#include <hip/hip_runtime.h>
#include <hip/hip_bf16.h>

#define NB 8
#define NN 256
#define DIMV 256
#define DI 64
#define NEGMAX 3.402823466e+38f

typedef unsigned short u16;
typedef unsigned int u32;
typedef __attribute__((ext_vector_type(8))) short bf16x8;
typedef __attribute__((ext_vector_type(4))) float f32x4;
typedef __attribute__((ext_vector_type(2))) float f32x2;
typedef __attribute__((ext_vector_type(2))) unsigned int u32x2;

__device__ __forceinline__ u16 f2bf(float f) {
    __hip_bfloat16 h = __float2bfloat16(f);
    u16 u; __builtin_memcpy(&u, &h, 2); return u;
}
__device__ __forceinline__ u32 pack2(float a, float b) {
    return (u32)f2bf(a) | ((u32)f2bf(b) << 16);
}
__device__ __forceinline__ float ubf_lo(u32 u) {
    union { u32 u; float f; } x; x.u = u << 16; return x.f;
}
__device__ __forceinline__ float ubf_hi(u32 u) {
    union { u32 u; float f; } x; x.u = u & 0xffff0000u; return x.f;
}
// swizzles: fA for 128B-stride rows, fB for 64B-stride rows (bits 4-6 only)
__device__ __forceinline__ int fA(int row) { return ((row & 7) << 4) ^ ((row & 8) << 2); }
__device__ __forceinline__ int fB(int row) { return ((row >> 1) & 7) << 4; }

// ---------------------------------------------------------------------------
// merged prep, 576 blocks: [0,512) = qkv; [512,576) = fragment-major weights.
// ---------------------------------------------------------------------------
__global__ void prep_all(const float* __restrict__ x, const float* __restrict__ y,
                         const float* __restrict__ tw, const float* __restrict__ pw,
                         const float* __restrict__ gw,
                         const float* __restrict__ w1, const float* __restrict__ w2,
                         const float* __restrict__ pw2,
                         const float* __restrict__ pw1, const float* __restrict__ pb1,
                         float* __restrict__ q, float* __restrict__ k, float* __restrict__ v,
                         u16* __restrict__ w1s, u16* __restrict__ w2s,
                         u16* __restrict__ pw2s, u16* __restrict__ pw1f)
{
    __shared__ float xs[4][256];
    __shared__ float ys[4][256];
    const int blk = blockIdx.x;
    const int tid = threadIdx.x;

    if (blk >= 512) {                       // ---- weight fragments ----
        const int idx = (blk - 512) * 256 + tid;   // [0,16384)
        const int e   = idx & 7;
        const int l   = (idx >> 3) & 63;
        const int l15 = l & 15, lh = l >> 4;
        {   // w1s
            const int frag = idx >> 9;      // 0..31
            const int ks = frag & 1, c2 = (frag >> 1) & 1, hc = frag >> 2;
            w1s[idx] = f2bf(w1[(ks * 32 + lh * 8 + e) * 256 + hc * 32 + 2 * l15 + c2]);
        }
        {   // w2s
            const int frag = idx >> 9;      // 0..31
            const int ct = frag & 3, hc = frag >> 2;
            w2s[idx] = f2bf(w2[(hc * 32 + lh * 8 + e) * 64 + 4 * l15 + ct]);
        }
        if (idx < 4096) {                   // pw2s
            const int frag = idx >> 9;      // 0..7
            const int ks = frag & 1, ct = frag >> 1;
            pw2s[idx] = f2bf(pw2[(ks * 32 + lh * 8 + e) * 64 + 4 * l15 + ct]);
        }
        if (idx < 2048) {                   // pw1f (augmented, K=32 padded)
            const int ct = idx >> 9;        // 0..3
            const int kk = lh * 8 + e;
            const int col = 4 * l15 + ct;
            float val = (kk < 3) ? pw1[kk * 64 + col] : ((kk == 3) ? pb1[col] : 0.f);
            pw1f[idx] = f2bf(val);
        }
        return;
    }

    // ---- qkv: b = blk>>6, 4 rows, thread = (nl, d) ----
    const int b = blk >> 6;
    const int n0 = (blk & 63) * 4;
    {
        int r = tid >> 6, e = tid & 63;
        ((float4*)xs[r])[e] = ((const float4*)(x + (size_t)(b * NN + n0 + r) * DIMV))[e];
        ((float4*)ys[r])[e] = ((const float4*)(y + (size_t)(b * NN + n0 + r) * DIMV))[e];
    }
    __syncthreads();
    const int nl = tid >> 6, d = tid & 63;
    float aq = 0.f, ak = 0.f, av = 0.f;
    #pragma unroll 4
    for (int c = 0; c < 256; ++c) {
        float wq = tw[c * 64 + d], wk = pw[c * 64 + d], wv = gw[c * 64 + d];
        float xv = xs[nl][c], yv = ys[nl][c];
        aq += xv * wq; ak += yv * wk; av += yv * wv;
    }
    const int n = n0 + nl;
    q[(b * NN + n) * DI + d] = aq;
    k[(b * NN + n) * DI + d] = ak;
    v[(b * NN + n) * DI + d] = av;
}

// ---------------------------------------------------------------------------
// main fused kernel: one block per (b, i); 4 waves; wave owns rows j0..j0+63.
// r12 structure + flash-style cross-wave softmax combine: each wave exps with
// its WAVE-LOCAL max (no global-max wait), writes (m,s,a) into its private
// sHid slice (dead post-chunk-loop -> race-free pre-barrier), then ONE barrier
// + rescale combine.  Barriers 4 -> 2.   [r13 == measured best: 76.5us]
// ---------------------------------------------------------------------------
__global__ __launch_bounds__(256, 2)
void fused_attn(const float* __restrict__ x, const float* __restrict__ x_pos,
                const float* __restrict__ y_pos, const int* __restrict__ mask,
                const float* __restrict__ pb2,
                const float* __restrict__ ab1, const float* __restrict__ ab2,
                const float* __restrict__ out_w,
                const float* __restrict__ qg, const float* __restrict__ kg,
                const float* __restrict__ vg,
                const u16* __restrict__ w1s, const u16* __restrict__ w2s,
                const u16* __restrict__ pw2s, const u16* __restrict__ pw1f,
                float* __restrict__ out)
{
    __shared__ __align__(16) char sT[4][8192];     // 32 KB
    __shared__ __align__(16) char sHid[4][4096];   // 16 KB (hid dbuf -> Hc -> red)
    __shared__ __align__(16) char sV2[4][4096];    // 16 KB

    const int blk = blockIdx.x;
    const int b = blk >> 8;
    const int i = blk & 255;
    const int tid = threadIdx.x;
    const int l   = tid & 63;
    const int w   = tid >> 6;
    const int j0  = w * 64;
    const int l15 = l & 15;
    const int lh  = l >> 4;

    char* const sTw   = sT[w];
    char* const sHidw = sHid[w];
    char* const sV2w  = sV2[w];

    // hoisted LDS addresses
    int stW[4], hcW[4];
    #pragma unroll
    for (int r = 0; r < 4; ++r) {
        const int lr = lh * 4 + r;
        stW[r] = (lr * 128 + l15 * 8) ^ fA(lr);
        hcW[r] = (lr * 64 + l15 * 4) ^ fB(lr);
    }
    const int stR0 = (l15 * 128 + lh * 16) ^ fA(l15);
    const int stR1 = stR0 ^ 64;
    const int hcR  = (l15 * 64 + lh * 16) ^ fB(l15);

    // ---- mask ----
    const int mjl = mask[b * NN + j0 + l];
    const unsigned long long mb = __ballot(mjl != 0);
    const bool mi_b = mask[b * NN + i] != 0;

    // ---- phase 0: rel-pos A-fragments (bias-in-K: [r0,r1,r2,1,0..0]) ----
    const float xp0 = x_pos[(b * NN + i) * 3 + 0];
    const float xp1 = x_pos[(b * NN + i) * 3 + 1];
    const float xp2 = x_pos[(b * NN + i) * 3 + 2];

    bf16x8 afr[4];
    #pragma unroll
    for (int rt = 0; rt < 4; ++rt) {
        const float* yp = y_pos + (size_t)(b * NN + j0 + rt * 16 + l15) * 3;
        const float r0 = xp0 - yp[0], r1 = xp1 - yp[1], r2 = xp2 - yp[2];
        union { u32 u[4]; bf16x8 v; } c;
        c.u[0] = (lh == 0) ? pack2(r0, r1) : 0u;
        c.u[1] = (lh == 0) ? pack2(r2, 1.0f) : 0u;
        c.u[2] = 0u; c.u[3] = 0u;
        afr[rt] = c.v;
    }
    bf16x8 pw1b[4];
    #pragma unroll
    for (int ct = 0; ct < 4; ++ct)
        pw1b[ct] = *(const bf16x8*)(pw1f + (ct * 64 + l) * 8);

    const f32x4 qv   = *(const f32x4*)&qg[((size_t)b * NN + i) * DI + 4 * l15];
    const f32x4 pb2v = *(const f32x4*)&pb2[4 * l15];
    bf16x8 bfr[4][2];
    #pragma unroll
    for (int ct = 0; ct < 4; ++ct)
        #pragma unroll
        for (int ks = 0; ks < 2; ++ks)
            bfr[ct][ks] = *(const bf16x8*)(pw2s + ((ct * 2 + ks) * 64 + l) * 8);

    // hidden pipeline helpers (hA transient; dbuf in sHidw)
    f32x4 hA[4];
    #define HID_MFMA(RT)                                                        \
        { _Pragma("unroll") for (int ct = 0; ct < 4; ++ct) {                    \
            f32x4 z = {0.f, 0.f, 0.f, 0.f};                                     \
            hA[ct] = __builtin_amdgcn_mfma_f32_16x16x32_bf16(afr[RT], pw1b[ct], z, 0, 0, 0); } }
    #define HID_STORE(RT)                                                       \
        { char* hb = sHidw + (((RT) & 1) ? 2048 : 0);                           \
          _Pragma("unroll") for (int r = 0; r < 4; ++r) {                       \
            u32x2 hpk;                                                          \
            hpk[0] = pack2(fmaxf(hA[0][r], 0.f), fmaxf(hA[1][r], 0.f));         \
            hpk[1] = pack2(fmaxf(hA[2][r], 0.f), fmaxf(hA[3][r], 0.f));         \
            *(u32x2*)(hb + stW[r]) = hpk; } }

    // ---- rt loop: hid(rt+1) pipelined against GEMM0(rt)+epilogue(rt) ----
    u32x2 accVp[2][4];
    HID_MFMA(0);
    HID_STORE(0);
    #pragma unroll
    for (int rt = 0; rt < 4; ++rt) {
        if (rt < 3) { HID_MFMA(rt + 1); HID_STORE(rt + 1); }
        char* const hb = sHidw + ((rt & 1) ? 2048 : 0);
        const bf16x8 afc0 = *(const bf16x8*)(hb + stR0);
        const bf16x8 afc1 = *(const bf16x8*)(hb + stR1);

        // GEMM0: RPE = hidden @ pos_w2 (pb2 folded into acc init)
        f32x4 accR[4];
        #pragma unroll
        for (int ct = 0; ct < 4; ++ct) {
            f32x4 a = {pb2v[ct], pb2v[ct], pb2v[ct], pb2v[ct]};
            a = __builtin_amdgcn_mfma_f32_16x16x32_bf16(afc0, bfr[ct][0], a, 0, 0, 0);
            a = __builtin_amdgcn_mfma_f32_16x16x32_bf16(afc1, bfr[ct][1], a, 0, 0, 0);
            accR[ct] = a;
        }
        #pragma unroll
        for (int r = 0; r < 4; ++r) {
            const int row = j0 + rt * 16 + lh * 4 + r;
            const f32x4 kv = *(const f32x4*)&kg[((size_t)b * NN + row) * DI + 4 * l15];
            const f32x4 vv = *(const f32x4*)&vg[((size_t)b * NN + row) * DI + 4 * l15];
            float tv[4], vf[4];
            #pragma unroll
            for (int ct = 0; ct < 4; ++ct) {
                const float rpe = accR[ct][r];
                tv[ct] = qv[ct] - kv[ct] + rpe;
                vf[ct] = vv[ct] + rpe;
            }
            u32x2 tpk; tpk[0] = pack2(tv[0], tv[1]); tpk[1] = pack2(tv[2], tv[3]);
            u32x2 vpk; vpk[0] = pack2(vf[0], vf[1]); vpk[1] = pack2(vf[2], vf[3]);
            *(u32x2*)(sTw + stW[r] + rt * 2048) = tpk;      // deferred-read slice
            if (rt < 2) accVp[rt][r] = vpk;
            else        *(u32x2*)(sV2w + stW[r] + (rt - 2) * 2048) = vpk;
        }
    }

    // ---- deferred aT hoist (writes long completed -> no exposed RTT) ----
    bf16x8 aT[4][2];
    #pragma unroll
    for (int rt = 0; rt < 4; ++rt) {
        aT[rt][0] = *(const bf16x8*)(sTw + stR0 + rt * 2048);
        aT[rt][1] = *(const bf16x8*)(sTw + stR1 + rt * 2048);
    }

    // ---- chunk loop (full unroll): 8 chunks of 32 hidden; Hc in sHidw ----
    const f32x4 ab2v = *(const f32x4*)&ab2[4 * l15];
    f32x4 accS[4][4];
    #pragma unroll
    for (int rt = 0; rt < 4; ++rt)
        #pragma unroll
        for (int ct = 0; ct < 4; ++ct)
            accS[rt][ct] = (f32x4){ab2v[ct], ab2v[ct], ab2v[ct], ab2v[ct]};  // ab2 folded

    #pragma unroll
    for (int hc = 0; hc < 8; ++hc) {
        bf16x8 b1f[2][2];
        #pragma unroll
        for (int c2 = 0; c2 < 2; ++c2)
            #pragma unroll
            for (int ks = 0; ks < 2; ++ks)
                b1f[c2][ks] = *(const bf16x8*)(w1s + ((hc * 4 + c2 * 2 + ks) * 64 + l) * 8);
        bf16x8 b2f[4];
        #pragma unroll
        for (int ct = 0; ct < 4; ++ct)
            b2f[ct] = *(const bf16x8*)(w2s + ((hc * 4 + ct) * 64 + l) * 8);
        const f32x2 ab1v = *(const f32x2*)&ab1[hc * 32 + 2 * l15];
        const f32x4 ib0 = {ab1v[0], ab1v[0], ab1v[0], ab1v[0]};
        const f32x4 ib1 = {ab1v[1], ab1v[1], ab1v[1], ab1v[1]};
        __builtin_amdgcn_s_setprio(1);
        #pragma unroll
        for (int rt = 0; rt < 4; ++rt) {
            f32x4 h0 = ib0, h1 = ib1;                  // ab1 folded
            h0 = __builtin_amdgcn_mfma_f32_16x16x32_bf16(aT[rt][0], b1f[0][0], h0, 0, 0, 0);
            h0 = __builtin_amdgcn_mfma_f32_16x16x32_bf16(aT[rt][1], b1f[0][1], h0, 0, 0, 0);
            h1 = __builtin_amdgcn_mfma_f32_16x16x32_bf16(aT[rt][0], b1f[1][0], h1, 0, 0, 0);
            h1 = __builtin_amdgcn_mfma_f32_16x16x32_bf16(aT[rt][1], b1f[1][1], h1, 0, 0, 0);
            #pragma unroll
            for (int r = 0; r < 4; ++r)
                *(u32*)(sHidw + hcW[r] + rt * 1024) =
                    pack2(fmaxf(h0[r], 0.f), fmaxf(h1[r], 0.f));
        }
        // hoist all 4 a2 reads ahead of the MFMA chain (batch ds latency)
        bf16x8 a2[4];
        #pragma unroll
        for (int rt = 0; rt < 4; ++rt)
            a2[rt] = *(const bf16x8*)(sHidw + hcR + rt * 1024);
        #pragma unroll
        for (int rt = 0; rt < 4; ++rt)
            #pragma unroll
            for (int ct = 0; ct < 4; ++ct)
                accS[rt][ct] = __builtin_amdgcn_mfma_f32_16x16x32_bf16(a2[rt], b2f[ct], accS[rt][ct], 0, 0, 0);
        __builtin_amdgcn_s_setprio(0);
    }

    // ---- softmax: mask + WAVE-LOCAL max, exp immediately (no global wait) ----
    float mx[4] = {-NEGMAX, -NEGMAX, -NEGMAX, -NEGMAX};
    #pragma unroll
    for (int rt = 0; rt < 4; ++rt)
        #pragma unroll
        for (int r = 0; r < 4; ++r) {
            const int ro = rt * 16 + lh * 4 + r;
            const bool bit = mi_b && ((mb >> ro) & 1ull);
            #pragma unroll
            for (int ct = 0; ct < 4; ++ct) {
                float s = bit ? accS[rt][ct][r] : -NEGMAX;
                accS[rt][ct][r] = s;
                mx[ct] = fmaxf(mx[ct], s);
            }
        }
    #pragma unroll
    for (int ct = 0; ct < 4; ++ct) {
        mx[ct] = fmaxf(mx[ct], __shfl_xor(mx[ct], 16));
        mx[ct] = fmaxf(mx[ct], __shfl_xor(mx[ct], 32));
    }
    float ssum[4] = {0.f, 0.f, 0.f, 0.f}, sagg[4] = {0.f, 0.f, 0.f, 0.f};
    #pragma unroll
    for (int rt = 0; rt < 4; ++rt)
        #pragma unroll
        for (int r = 0; r < 4; ++r) {
            u32x2 vpk;
            if (rt < 2) vpk = accVp[rt][r];
            else        vpk = *(const u32x2*)(sV2w + stW[r] + (rt - 2) * 2048);
            const float vfs[4] = {ubf_lo(vpk[0]), ubf_hi(vpk[0]), ubf_lo(vpk[1]), ubf_hi(vpk[1])};
            #pragma unroll
            for (int ct = 0; ct < 4; ++ct) {
                const float e = __expf(accS[rt][ct][r] - mx[ct]);
                ssum[ct] += e;
                sagg[ct] += e * vfs[ct];
            }
        }
    #pragma unroll
    for (int ct = 0; ct < 4; ++ct) {
        ssum[ct] += __shfl_xor(ssum[ct], 16);
        ssum[ct] += __shfl_xor(ssum[ct], 32);
        sagg[ct] += __shfl_xor(sagg[ct], 16);
        sagg[ct] += __shfl_xor(sagg[ct], 32);
    }
    // write (m, s, a) into OWN sHid slice (wave-private, dead) - pre-barrier OK
    {
        float* const redW = (float*)&sHid[w][0];
        if (lh == 0) {
            *(f32x4*)&redW[      4 * l15] = (f32x4){mx[0], mx[1], mx[2], mx[3]};
            *(f32x4*)&redW[ 64 + 4 * l15] = (f32x4){ssum[0], ssum[1], ssum[2], ssum[3]};
            *(f32x4*)&redW[128 + 4 * l15] = (f32x4){sagg[0], sagg[1], sagg[2], sagg[3]};
        }
    }
    __syncthreads();
    // flash combine: M = max m_w; den = sum s_w e^{m_w-M}; num = sum a_w e^{m_w-M}
    float* const redAll = (float*)&sHid[0][0];     // slices at float offset w*1024
    if (tid < 64) {
        const float m0 = redAll[tid],        m1 = redAll[1024 + tid],
                    m2 = redAll[2048 + tid], m3 = redAll[3072 + tid];
        const float M = fmaxf(fmaxf(m0, m1), fmaxf(m2, m3));
        const float e0 = __expf(m0 - M), e1 = __expf(m1 - M),
                    e2 = __expf(m2 - M), e3 = __expf(m3 - M);
        const float den = redAll[64 + tid] * e0 + redAll[1024 + 64 + tid] * e1
                        + redAll[2048 + 64 + tid] * e2 + redAll[3072 + 64 + tid] * e3;
        const float num = redAll[128 + tid] * e0 + redAll[1024 + 128 + tid] * e1
                        + redAll[2048 + 128 + tid] * e2 + redAll[3072 + 128 + tid] * e3;
        redAll[192 + tid] = num / den;
    }
    __syncthreads();

    // ---- out[i,:] = x[i,:] + agg @ out_w ----
    {
        float acc = 0.f;
        #pragma unroll 16
        for (int d = 0; d < 64; ++d)
            acc += redAll[192 + d] * out_w[d * DIMV + tid];
        const int o = (b * NN + i) * DIMV + tid;
        out[o] = x[o] + acc;
    }
}

// ---------------------------------------------------------------------------
extern "C" void kernel_launch(void* const* d_in, const int* in_sizes, int n_in,
                              void* d_out, int out_size, void* d_ws, size_t ws_size,
                              hipStream_t stream)
{
    const float* x       = (const float*)d_in[0];
    const float* y       = (const float*)d_in[1];
    const float* x_pos   = (const float*)d_in[2];
    const float* y_pos   = (const float*)d_in[3];
    const int*   mask    = (const int*)d_in[4];
    const float* g_w     = (const float*)d_in[5];
    const float* theta_w = (const float*)d_in[6];
    const float* phi_w   = (const float*)d_in[7];
    const float* pos_w1  = (const float*)d_in[8];
    const float* pos_b1  = (const float*)d_in[9];
    const float* pos_w2  = (const float*)d_in[10];
    const float* pos_b2  = (const float*)d_in[11];
    const float* attn_w1 = (const float*)d_in[12];
    const float* attn_b1 = (const float*)d_in[13];
    const float* attn_w2 = (const float*)d_in[14];
    const float* attn_b2 = (const float*)d_in[15];
    const float* out_w   = (const float*)d_in[16];

    float* q = (float*)d_ws;
    float* k = q + NB * NN * DI;
    float* v = k + NB * NN * DI;
    u16* w1s  = (u16*)(v + NB * NN * DI);   // 16384 u16 (fragment-major)
    u16* w2s  = w1s + 16384;                // 16384 u16
    u16* pw2s = w2s + 16384;                // 4096 u16
    u16* pw1f = pw2s + 4096;                // 2048 u16

    prep_all<<<576, 256, 0, stream>>>(x, y, theta_w, phi_w, g_w,
                                      attn_w1, attn_w2, pos_w2, pos_w1, pos_b1,
                                      q, k, v, w1s, w2s, pw2s, pw1f);
    fused_attn<<<NB * NN, 256, 0, stream>>>(x, x_pos, y_pos, mask,
                                            pos_b2, attn_b1, attn_b2, out_w,
                                            q, k, v, w1s, w2s, pw2s, pw1f,
                                            (float*)d_out);
}